// Round 12
// baseline (378.250 us; speedup 1.0000x reference)
//
#include <hip/hip_runtime.h>
#include <math.h>

#define N_NODES 50000
#define N_EDGES 800000
#define E_TOT   850000   // + self loops
#define N_GRAPHS 64
#define EMB 128
#define HID 64
#define HEADS 4
#define NEG_SLOPE 0.2f
#define EPS 1e-16f
#define MAX_DEG 64

typedef short bf16x8 __attribute__((ext_vector_type(8)));
typedef float f32x4  __attribute__((ext_vector_type(4)));

__device__ __forceinline__ float leaky(float x) { return x >= 0.f ? x : NEG_SLOPE * x; }
__device__ __forceinline__ float elu(float x)   { return x > 0.f ? x : expf(x) - 1.f; }

__device__ __forceinline__ unsigned short f2bf(float f) {
    unsigned u = __float_as_uint(f);
    return (unsigned short)((u + 0x7FFFu + ((u >> 16) & 1u)) >> 16);
}
__device__ __forceinline__ float bf2f(unsigned short h) {
    return __uint_as_float((unsigned)h << 16);
}

__device__ __forceinline__ void edge_sd(const int* __restrict__ ei, int e, int& s, int& d) {
    if (e < N_EDGES) { s = ei[e]; d = ei[N_EDGES + e]; }
    else             { s = d = e - N_EDGES; }
}

__device__ __forceinline__ int lbound(const int* __restrict__ a, int n, int v) {
    int lo = 0, hi = n;
    while (lo < hi) { int mid = (lo + hi) >> 1; if (a[mid] < v) lo = mid + 1; else hi = mid; }
    return lo;
}

// ---- zero fill ----
__global__ void k_zero4(float4* p, int n4) {
    int i = blockIdx.x * blockDim.x + threadIdx.x;
    int stride = gridDim.x * blockDim.x;
    for (; i < n4; i += stride) p[i] = make_float4(0.f, 0.f, 0.f, 0.f);
}

// ---- ELL adjacency build ----
__global__ void k_ell_build(const int* __restrict__ ei, unsigned* __restrict__ cnt,
                            unsigned short* __restrict__ ell) {
    int e = blockIdx.x * blockDim.x + threadIdx.x;
    if (e >= E_TOT) return;
    int s, d; edge_sd(ei, e, s, d);
    unsigned slot = atomicAdd(&cnt[d], 1u);
    if (slot < MAX_DEG) ell[d * MAX_DEG + slot] = (unsigned short)s;
}

// ---- weight prep (parallel) ----
__global__ void k_wprep(const float* __restrict__ W1, const float* __restrict__ as1, const float* __restrict__ ad1,
                        const float* __restrict__ W2, const float* __restrict__ as2, const float* __restrict__ ad2,
                        const float* __restrict__ Wg1,
                        unsigned short* __restrict__ W1t, float* __restrict__ v1s, float* __restrict__ v1d,
                        unsigned short* __restrict__ W2t, float* __restrict__ v2s, float* __restrict__ v2d,
                        unsigned short* __restrict__ wg1h, unsigned short* __restrict__ wg1l) {
    int b = blockIdx.x, t = threadIdx.x;
    if (b < 32) {
        for (int i = b * 1024 + t; i < (b + 1) * 1024; i += 256) {
            int c = i >> 7, k = i & 127;
            W1t[i] = f2bf(W1[k * 256 + c]);
        }
    } else if (b < 48) {
        int bb = b - 32;
        for (int i = bb * 1024 + t; i < (bb + 1) * 1024; i += 256) {
            int c = i >> 8, k = i & 255;
            W2t[i] = f2bf(W2[k * 64 + c]);
        }
    } else if (b == 48) {
        for (int i = t; i < 512; i += 256) {
            int h = i >> 7, k = i & 127;
            float s = 0.f, d = 0.f;
            for (int c = 0; c < 64; ++c) {
                float wv = W1[k * 256 + h * 64 + c];
                s = fmaf(wv, as1[h * 64 + c], s);
                d = fmaf(wv, ad1[h * 64 + c], d);
            }
            v1s[i] = s; v1d[i] = d;
        }
    } else if (b == 49) {
        float s = 0.f, d = 0.f;
        for (int cc = 0; cc < 64; ++cc) {
            float wv = W2[t * 64 + cc];
            s = fmaf(wv, as2[cc], s);
            d = fmaf(wv, ad2[cc], d);
        }
        v2s[t] = s; v2d[t] = d;
    } else {
        for (int i = t; i < 4096; i += 256) {
            int c = i >> 6, k = i & 63;
            float v = Wg1[k * 64 + c];
            unsigned short h = f2bf(v);
            wg1h[i] = h;
            wg1l[i] = f2bf(v - bf2f(h));
        }
    }
}

// ---- layer 1 GEMM via MFMA + fused logit dots; output to 8 channel-planes h1p[slice][N][32] ----
__global__ __launch_bounds__(256)
void k_gemm1_mfma(const float* __restrict__ x, const unsigned short* __restrict__ W1t,
                  const float* __restrict__ v1s, const float* __restrict__ v1d,
                  unsigned short* __restrict__ h1p, float* __restrict__ a_src1,
                  float* __restrict__ a_dst1) {
    int w = threadIdx.x >> 6, l = threadIdx.x & 63;
    int r = l & 15, kg = l >> 4;
    int tile = blockIdx.x;
    const float* xr = x + (size_t)(tile * 16 + r) * 128 + kg * 8;
    bf16x8 af[4];
    float ps = 0.f, pd = 0.f;
    #pragma unroll
    for (int j = 0; j < 4; ++j) {
        float4 f0 = *(const float4*)(xr + j * 32);
        float4 f1 = *(const float4*)(xr + j * 32 + 4);
        const float* vs = v1s + w * 128 + j * 32 + kg * 8;
        const float* vd = v1d + w * 128 + j * 32 + kg * 8;
        float4 s0 = *(const float4*)vs, s1 = *(const float4*)(vs + 4);
        float4 d0 = *(const float4*)vd, d1 = *(const float4*)(vd + 4);
        ps += f0.x*s0.x + f0.y*s0.y + f0.z*s0.z + f0.w*s0.w
            + f1.x*s1.x + f1.y*s1.y + f1.z*s1.z + f1.w*s1.w;
        pd += f0.x*d0.x + f0.y*d0.y + f0.z*d0.z + f0.w*d0.w
            + f1.x*d1.x + f1.y*d1.y + f1.z*d1.z + f1.w*d1.w;
        bf16x8 t;
        t[0] = (short)f2bf(f0.x); t[1] = (short)f2bf(f0.y);
        t[2] = (short)f2bf(f0.z); t[3] = (short)f2bf(f0.w);
        t[4] = (short)f2bf(f1.x); t[5] = (short)f2bf(f1.y);
        t[6] = (short)f2bf(f1.z); t[7] = (short)f2bf(f1.w);
        af[j] = t;
    }
    ps += __shfl_xor(ps, 16); ps += __shfl_xor(ps, 32);
    pd += __shfl_xor(pd, 16); pd += __shfl_xor(pd, 32);
    if (l < 16) {
        a_src1[(size_t)(tile * 16 + r) * 4 + w] = ps;
        a_dst1[(size_t)(tile * 16 + r) * 4 + w] = pd;
    }
    for (int cc = 0; cc < 4; ++cc) {
        int c0 = cc * 64 + w * 16;
        const bf16x8* B = (const bf16x8*)(W1t + (size_t)(c0 + r) * 128 + kg * 8);
        f32x4 acc = {0.f, 0.f, 0.f, 0.f};
        acc = __builtin_amdgcn_mfma_f32_16x16x32_bf16(af[0], B[0],  acc, 0, 0, 0);
        acc = __builtin_amdgcn_mfma_f32_16x16x32_bf16(af[1], B[4],  acc, 0, 0, 0);
        acc = __builtin_amdgcn_mfma_f32_16x16x32_bf16(af[2], B[8],  acc, 0, 0, 0);
        acc = __builtin_amdgcn_mfma_f32_16x16x32_bf16(af[3], B[12], acc, 0, 0, 0);
        int c = c0 + r;
        int plane = c >> 5, within = c & 31;
        #pragma unroll
        for (int j = 0; j < 4; ++j) {
            int nr = tile * 16 + kg * 4 + j;
            h1p[((size_t)plane * N_NODES + nr) * 32 + within] = f2bf(acc[j]);
        }
    }
}

// ---- attention softmax (once per node): pack (src<<16)|bf16(w_h) into per-head planes ----
__global__ __launch_bounds__(256)
void k_attn1(const unsigned short* __restrict__ ell, const unsigned* __restrict__ cnt,
             const float4* __restrict__ asrc, const float4* __restrict__ adst,
             unsigned* __restrict__ wele) {
    int wave = threadIdx.x >> 6, lane = threadIdx.x & 63;
    int node = blockIdx.x * 4 + wave;
    int deg = min((int)cnt[node], MAX_DEG);

    float4 ad = adst[node];
    float a0 = -INFINITY, a1 = -INFINITY, a2 = -INFINITY, a3 = -INFINITY;
    int s = 0;
    if (lane < deg) {
        s = ell[node * MAX_DEG + lane];
        float4 as = asrc[s];
        a0 = leaky(as.x + ad.x); a1 = leaky(as.y + ad.y);
        a2 = leaky(as.z + ad.z); a3 = leaky(as.w + ad.w);
    }
    float m0 = a0, m1 = a1, m2 = a2, m3 = a3;
    for (int o = 32; o > 0; o >>= 1) {
        m0 = fmaxf(m0, __shfl_xor(m0, o)); m1 = fmaxf(m1, __shfl_xor(m1, o));
        m2 = fmaxf(m2, __shfl_xor(m2, o)); m3 = fmaxf(m3, __shfl_xor(m3, o));
    }
    float w0 = lane < deg ? expf(a0 - m0) : 0.f;
    float w1 = lane < deg ? expf(a1 - m1) : 0.f;
    float w2 = lane < deg ? expf(a2 - m2) : 0.f;
    float w3 = lane < deg ? expf(a3 - m3) : 0.f;
    float t0 = w0, t1 = w1, t2 = w2, t3 = w3;
    for (int o = 32; o > 0; o >>= 1) {
        t0 += __shfl_xor(t0, o); t1 += __shfl_xor(t1, o);
        t2 += __shfl_xor(t2, o); t3 += __shfl_xor(t3, o);
    }
    w0 /= (t0 + EPS); w1 /= (t1 + EPS); w2 /= (t2 + EPS); w3 /= (t3 + EPS);
    if (lane < deg) {
        unsigned hi = (unsigned)s << 16;
        size_t base = (size_t)node * 64 + lane;
        wele[base]                            = hi | f2bf(w0);
        wele[(size_t)N_NODES * 64 + base]     = hi | f2bf(w1);
        wele[(size_t)N_NODES * 64 * 2 + base] = hi | f2bf(w2);
        wele[(size_t)N_NODES * 64 * 3 + base] = hi | f2bf(w3);
    }
}

// ---- XCD-sliced layer-1 gather: slice = blockIdx%8 (pins channel plane to one XCD's L2) ----
__global__ __launch_bounds__(256)
void k_gather1(const unsigned* __restrict__ wele, const unsigned* __restrict__ cnt,
               const unsigned short* __restrict__ h1p, const float* __restrict__ bias,
               const float* __restrict__ v2s, const float* __restrict__ v2d,
               unsigned short* __restrict__ out1b,
               float* __restrict__ p2s, float* __restrict__ p2d) {
    int b = blockIdx.x;
    int slice = b & 7, tile = b >> 3;
    int wave = threadIdx.x >> 6, lane = threadIdx.x & 63;
    int head = slice >> 1;
    const unsigned* wp = wele + (size_t)head * N_NODES * 64;
    const unsigned short* hp = h1p + (size_t)slice * N_NODES * 32;
    int cbase = slice * 32 + (lane & 7) * 4;
    float4 bb = *(const float4*)(bias + cbase);
    float4 vs = *(const float4*)(v2s + cbase);
    float4 vd = *(const float4*)(v2d + cbase);
    #pragma unroll
    for (int j = 0; j < 4; ++j) {
        int node = tile * 16 + wave * 4 + j;
        int deg = min((int)cnt[node], MAX_DEG);
        unsigned entry = lane < deg ? wp[(size_t)node * 64 + lane] : 0u;
        float a0 = 0.f, a1 = 0.f, a2 = 0.f, a3 = 0.f;
        for (int e0 = 0; e0 < deg; e0 += 8) {
            int row = e0 + (lane >> 3);
            unsigned ue = __shfl(entry, row);
            if (row < deg) {
                int s = ue >> 16;
                float w = bf2f((unsigned short)(ue & 0xffffu));
                ushort4 h = *(const ushort4*)(hp + (size_t)s * 32 + (lane & 7) * 4);
                a0 = fmaf(bf2f(h.x), w, a0); a1 = fmaf(bf2f(h.y), w, a1);
                a2 = fmaf(bf2f(h.z), w, a2); a3 = fmaf(bf2f(h.w), w, a3);
            }
        }
        a0 += __shfl_xor(a0, 8); a0 += __shfl_xor(a0, 16); a0 += __shfl_xor(a0, 32);
        a1 += __shfl_xor(a1, 8); a1 += __shfl_xor(a1, 16); a1 += __shfl_xor(a1, 32);
        a2 += __shfl_xor(a2, 8); a2 += __shfl_xor(a2, 16); a2 += __shfl_xor(a2, 32);
        a3 += __shfl_xor(a3, 8); a3 += __shfl_xor(a3, 16); a3 += __shfl_xor(a3, 32);
        float o0 = elu(a0 + bb.x), o1 = elu(a1 + bb.y), o2 = elu(a2 + bb.z), o3 = elu(a3 + bb.w);
        // exact f32 partial logit dots for layer 2
        float ps = o0 * vs.x + o1 * vs.y + o2 * vs.z + o3 * vs.w;
        float pd = o0 * vd.x + o1 * vd.y + o2 * vd.z + o3 * vd.w;
        ps += __shfl_xor(ps, 1); ps += __shfl_xor(ps, 2); ps += __shfl_xor(ps, 4);
        pd += __shfl_xor(pd, 1); pd += __shfl_xor(pd, 2); pd += __shfl_xor(pd, 4);
        if (lane < 8)
            *(ushort4*)(out1b + (size_t)node * 256 + cbase) =
                make_ushort4(f2bf(o0), f2bf(o1), f2bf(o2), f2bf(o3));
        if (lane == 0) {
            p2s[(size_t)node * 8 + slice] = ps;
            p2d[(size_t)node * 8 + slice] = pd;
        }
    }
}

// ---- layer 2 GEMM via MFMA + finish layer-2 logit dots ----
__global__ __launch_bounds__(256)
void k_gemm2_mfma(const unsigned short* __restrict__ amat, const unsigned short* __restrict__ W2t,
                  const float* __restrict__ p2s, const float* __restrict__ p2d,
                  unsigned short* __restrict__ h2b, float* __restrict__ a_src2,
                  float* __restrict__ a_dst2) {
    int w = threadIdx.x >> 6, l = threadIdx.x & 63;
    int r = l & 15, kg = l >> 4;
    int tile = blockIdx.x;
    const bf16x8* A = (const bf16x8*)(amat + (size_t)(tile * 16 + r) * 256 + kg * 8);
    const bf16x8* B = (const bf16x8*)(W2t + (size_t)(w * 16 + r) * 256 + kg * 8);
    f32x4 acc = {0.f, 0.f, 0.f, 0.f};
    #pragma unroll
    for (int kk = 0; kk < 8; ++kk)
        acc = __builtin_amdgcn_mfma_f32_16x16x32_bf16(A[kk * 4], B[kk * 4], acc, 0, 0, 0);
    #pragma unroll
    for (int j = 0; j < 4; ++j)
        h2b[(size_t)(tile * 16 + kg * 4 + j) * 64 + w * 16 + r] = f2bf(acc[j]);
    if (w == 0 && l < 16) {
        int node = tile * 16 + l;
        float s = 0.f, d = 0.f;
        #pragma unroll
        for (int j = 0; j < 8; ++j) {
            s += p2s[(size_t)node * 8 + j];
            d += p2d[(size_t)node * 8 + j];
        }
        a_src2[node] = s; a_dst2[node] = d;
    }
}

// ---- FUSED layer 2: node gather (H=1) then gate MFMA in-block ----
__global__ __launch_bounds__(1024)
void k_layer2(const unsigned short* __restrict__ ell, const unsigned* __restrict__ cnt,
              const float* __restrict__ asrc, const float* __restrict__ adst,
              const unsigned short* __restrict__ h2b, const float* __restrict__ bias,
              const unsigned short* __restrict__ wg1h, const unsigned short* __restrict__ wg1l,
              const float* __restrict__ bg1, const float* __restrict__ Wg2,
              const float* __restrict__ bg2,
              float* __restrict__ out2, float* __restrict__ gate) {
    __shared__ float sw[16][MAX_DEG];
    __shared__ int   ss[16][MAX_DEG];
    __shared__ unsigned short Ah[16][72], Al[16][72];
    __shared__ float gp[4][16];
    int wave = threadIdx.x >> 6, lane = threadIdx.x & 63;
    int half = lane >> 5, li = lane & 31;
    int node = blockIdx.x * 16 + wave;
    int deg = min((int)cnt[node], MAX_DEG);

    float adv = adst[node];
    float a = -INFINITY;
    int s = 0;
    if (lane < deg) {
        s = ell[node * MAX_DEG + lane];
        a = leaky(asrc[s] + adv);
    }
    float m = a;
    for (int o = 32; o > 0; o >>= 1) m = fmaxf(m, __shfl_xor(m, o));
    float w = lane < deg ? expf(a - m) : 0.f;
    float t = w;
    for (int o = 32; o > 0; o >>= 1) t += __shfl_xor(t, o);
    w /= (t + EPS);
    if (lane < deg) { sw[wave][lane] = w; ss[wave][lane] = s; }

    float c0 = 0.f, c1 = 0.f;
    for (int e = 0; e < deg; e += 2) {
        int row = e + half;
        if (row < deg) {
            int se = ss[wave][row];
            float ww = sw[wave][row];
            unsigned u = *(const unsigned*)(h2b + (size_t)se * 64 + li * 2);
            c0 = fmaf(__uint_as_float(u << 16), ww, c0);
            c1 = fmaf(__uint_as_float(u & 0xffff0000u), ww, c1);
        }
    }
    c0 += __shfl_xor(c0, 32);
    c1 += __shfl_xor(c1, 32);
    if (half == 0) {
        float o0 = elu(c0 + bias[li * 2]);
        float o1 = elu(c1 + bias[li * 2 + 1]);
        *(float2*)(out2 + (size_t)node * 64 + li * 2) = make_float2(o0, o1);
        unsigned short h0 = f2bf(o0), h1 = f2bf(o1);
        *(unsigned*)&Ah[wave][li * 2] = ((unsigned)h1 << 16) | h0;
        unsigned short l0 = f2bf(o0 - bf2f(h0)), l1 = f2bf(o1 - bf2f(h1));
        *(unsigned*)&Al[wave][li * 2] = ((unsigned)l1 << 16) | l0;
    }

    __syncthreads();
    if (wave < 4) {
        int r = lane & 15, kg = lane >> 4;
        const bf16x8* Bh = (const bf16x8*)(wg1h + (size_t)(wave * 16 + r) * 64 + kg * 8);
        const bf16x8* Bl = (const bf16x8*)(wg1l + (size_t)(wave * 16 + r) * 64 + kg * 8);
        bf16x8 ah0 = *(const bf16x8*)&Ah[r][kg * 8];
        bf16x8 ah1 = *(const bf16x8*)&Ah[r][kg * 8 + 32];
        bf16x8 al0 = *(const bf16x8*)&Al[r][kg * 8];
        bf16x8 al1 = *(const bf16x8*)&Al[r][kg * 8 + 32];
        f32x4 acc = {0.f, 0.f, 0.f, 0.f};
        acc = __builtin_amdgcn_mfma_f32_16x16x32_bf16(ah0, Bh[0], acc, 0, 0, 0);
        acc = __builtin_amdgcn_mfma_f32_16x16x32_bf16(ah1, Bh[4], acc, 0, 0, 0);
        acc = __builtin_amdgcn_mfma_f32_16x16x32_bf16(ah0, Bl[0], acc, 0, 0, 0);
        acc = __builtin_amdgcn_mfma_f32_16x16x32_bf16(ah1, Bl[4], acc, 0, 0, 0);
        acc = __builtin_amdgcn_mfma_f32_16x16x32_bf16(al0, Bh[0], acc, 0, 0, 0);
        acc = __builtin_amdgcn_mfma_f32_16x16x32_bf16(al1, Bh[4], acc, 0, 0, 0);
        int col = wave * 16 + r;
        float wg2 = Wg2[col], bb = bg1[col];
        float part[4];
        #pragma unroll
        for (int j = 0; j < 4; ++j) part[j] = fmaxf(acc[j] + bb, 0.f) * wg2;
        #pragma unroll
        for (int o = 8; o > 0; o >>= 1) {
            #pragma unroll
            for (int j = 0; j < 4; ++j) part[j] += __shfl_xor(part[j], o);
        }
        if (r == 0) {
            #pragma unroll
            for (int j = 0; j < 4; ++j) gp[wave][kg * 4 + j] = part[j];
        }
    }
    __syncthreads();
    if (threadIdx.x < 16)
        gate[blockIdx.x * 16 + threadIdx.x] = gp[0][threadIdx.x] + gp[1][threadIdx.x]
                                            + gp[2][threadIdx.x] + gp[3][threadIdx.x] + bg2[0];
}

// ---- per-graph softmax + weighted aggregation ----
__global__ __launch_bounds__(1024)
void k_final(const float* __restrict__ gate, const float* __restrict__ hfin,
             const int* __restrict__ batch, float* __restrict__ out) {
    __shared__ float red[16];
    __shared__ float redc[16][64];
    int g = blockIdx.x;
    int lo = lbound(batch, N_NODES, g);
    int hi = lbound(batch, N_NODES, g + 1);
    int tid = threadIdx.x, wave = tid >> 6, lane = tid & 63;

    float m = -INFINITY;
    for (int i = lo + tid; i < hi; i += 1024) m = fmaxf(m, gate[i]);
    for (int o = 32; o > 0; o >>= 1) m = fmaxf(m, __shfl_xor(m, o));
    if (lane == 0) red[wave] = m;
    __syncthreads();
    m = -INFINITY;
    #pragma unroll
    for (int i = 0; i < 16; ++i) m = fmaxf(m, red[i]);
    __syncthreads();

    float s = 0.f;
    for (int i = lo + tid; i < hi; i += 1024) s += expf(gate[i] - m);
    for (int o = 32; o > 0; o >>= 1) s += __shfl_xor(s, o);
    if (lane == 0) red[wave] = s;
    __syncthreads();
    s = 0.f;
    #pragma unroll
    for (int i = 0; i < 16; ++i) s += red[i];

    float acc = 0.f;
    for (int i = lo + wave; i < hi; i += 16)
        acc = fmaf(expf(gate[i] - m), hfin[(size_t)i * 64 + lane], acc);
    redc[wave][lane] = acc;
    __syncthreads();
    if (tid < 64) {
        float r = 0.f;
        #pragma unroll
        for (int i = 0; i < 16; ++i) r += redc[i][tid];
        out[g * 64 + tid] = r / (s + EPS);
    }
}

extern "C" void kernel_launch(void* const* d_in, const int* in_sizes, int n_in,
                              void* d_out, int out_size, void* d_ws, size_t ws_size,
                              hipStream_t stream) {
    const float* x    = (const float*)d_in[0];
    const int*   ei   = (const int*)d_in[1];
    const int*   batch= (const int*)d_in[2];
    const float* W1   = (const float*)d_in[3];
    const float* as1  = (const float*)d_in[4];
    const float* ad1  = (const float*)d_in[5];
    const float* b1   = (const float*)d_in[6];
    const float* W2   = (const float*)d_in[7];
    const float* as2  = (const float*)d_in[8];
    const float* ad2  = (const float*)d_in[9];
    const float* b2   = (const float*)d_in[10];
    const float* Wg1  = (const float*)d_in[11];
    const float* bg1  = (const float*)d_in[12];
    const float* Wg2  = (const float*)d_in[13];
    const float* bg2  = (const float*)d_in[14];
    float* out = (float*)d_out;

    char* W = (char*)d_ws;
    size_t off = 0;
    // ---- zeroed region: cnt only ----
    unsigned* cnt = (unsigned*)(W + off); off += (size_t)N_NODES * 4;
    size_t zero_bytes = off;
    // ---- fixed buffers ----
    unsigned short* ell  = (unsigned short*)(W + off); off += (size_t)N_NODES * MAX_DEG * 2; // 6.4 MB
    unsigned short* h1p  = (unsigned short*)(W + off); size_t h1_off = off;
    off += (size_t)N_NODES * 256 * 2;                                                        // 25.6 MB
    float* a_src1 = (float*)(W + off); off += (size_t)N_NODES * HEADS * 4;
    float* a_dst1 = (float*)(W + off); off += (size_t)N_NODES * HEADS * 4;
    unsigned* wele = (unsigned*)(W + off); off += (size_t)HEADS * N_NODES * MAX_DEG * 4;     // 51.2 MB
    unsigned short* out1b = (unsigned short*)(W + off); off += (size_t)N_NODES * 256 * 2;    // 25.6 MB
    float* p2s = (float*)(W + off); off += (size_t)N_NODES * 8 * 4;                          // 1.6 MB
    float* p2d = (float*)(W + off); off += (size_t)N_NODES * 8 * 4;                          // 1.6 MB
    float* gate   = (float*)(W + off); off += (size_t)N_NODES * 4;
    unsigned short* W1t = (unsigned short*)(W + off); off += (size_t)128 * 256 * 2;
    float* v1s = (float*)(W + off); off += 512 * 4;
    float* v1d = (float*)(W + off); off += 512 * 4;
    unsigned short* W2t = (unsigned short*)(W + off); off += (size_t)64 * 256 * 2;
    float* v2s = (float*)(W + off); off += 256 * 4;
    float* v2d = (float*)(W + off); off += 256 * 4;
    unsigned short* wg1h = (unsigned short*)(W + off); off += (size_t)64 * 64 * 2;
    unsigned short* wg1l = (unsigned short*)(W + off); off += (size_t)64 * 64 * 2;
    // ---- alias region inside h1p (dead after k_gather1) ----
    size_t aoff = h1_off;
    unsigned short* h2b = (unsigned short*)(W + aoff); aoff += (size_t)N_NODES * HID * 2;    // 6.4 MB
    float* out2   = (float*)(W + aoff); aoff += (size_t)N_NODES * HID * 4;                   // 12.8 MB
    float* a_src2 = (float*)(W + aoff); aoff += (size_t)N_NODES * 4;
    float* a_dst2 = (float*)(W + aoff); aoff += (size_t)N_NODES * 4;
    (void)ws_size; (void)in_sizes; (void)n_in; (void)out_size;

    k_zero4<<<64, 256, 0, stream>>>((float4*)W, (int)(zero_bytes / 16));
    k_ell_build<<<(E_TOT + 255) / 256, 256, 0, stream>>>(ei, cnt, ell);
    k_wprep<<<51, 256, 0, stream>>>(W1, as1, ad1, W2, as2, ad2, Wg1,
                                    W1t, v1s, v1d, W2t, v2s, v2d, wg1h, wg1l);

    // layer 1: GEMM (+logit dots) -> softmax weights -> XCD-sliced gather
    k_gemm1_mfma<<<N_NODES / 16, 256, 0, stream>>>(x, W1t, v1s, v1d, h1p, a_src1, a_dst1);
    k_attn1<<<N_NODES / 4, 256, 0, stream>>>(ell, cnt, (const float4*)a_src1,
                                             (const float4*)a_dst1, wele);
    k_gather1<<<(N_NODES / 16) * 8, 256, 0, stream>>>(wele, cnt, h1p, b1, v2s, v2d,
                                                      out1b, p2s, p2d);

    // layer 2 GEMM (+finish logit dots); h1p dead -> h2b/out2/a_src2 alias it
    k_gemm2_mfma<<<N_NODES / 16, 256, 0, stream>>>(out1b, W2t, p2s, p2d, h2b, a_src2, a_dst2);
    k_layer2<<<N_NODES / 16, 1024, 0, stream>>>(ell, cnt, a_src2, a_dst2, h2b, b2,
                                                wg1h, wg1l, bg1, Wg2, bg2, out2, gate);
    // per-graph softmax aggregation
    k_final<<<N_GRAPHS, 1024, 0, stream>>>(gate, out2, batch, out);
}

// Round 13
// 288.516 us; speedup vs baseline: 1.3110x; 1.3110x over previous
//
#include <hip/hip_runtime.h>
#include <math.h>

#define N_NODES 50000
#define N_EDGES 800000
#define E_TOT   850000   // + self loops
#define N_GRAPHS 64
#define EMB 128
#define HID 64
#define HEADS 4
#define NEG_SLOPE 0.2f
#define EPS 1e-16f
#define MAX_DEG 64

typedef short bf16x8 __attribute__((ext_vector_type(8)));
typedef float f32x4  __attribute__((ext_vector_type(4)));

__device__ __forceinline__ float leaky(float x) { return x >= 0.f ? x : NEG_SLOPE * x; }
__device__ __forceinline__ float elu(float x)   { return x > 0.f ? x : expf(x) - 1.f; }

__device__ __forceinline__ unsigned short f2bf(float f) {
    unsigned u = __float_as_uint(f);
    return (unsigned short)((u + 0x7FFFu + ((u >> 16) & 1u)) >> 16);
}
__device__ __forceinline__ float bf2f(unsigned short h) {
    return __uint_as_float((unsigned)h << 16);
}

__device__ __forceinline__ void edge_sd(const int* __restrict__ ei, int e, int& s, int& d) {
    if (e < N_EDGES) { s = ei[e]; d = ei[N_EDGES + e]; }
    else             { s = d = e - N_EDGES; }
}

__device__ __forceinline__ int lbound(const int* __restrict__ a, int n, int v) {
    int lo = 0, hi = n;
    while (lo < hi) { int mid = (lo + hi) >> 1; if (a[mid] < v) lo = mid + 1; else hi = mid; }
    return lo;
}

// ---- zero fill ----
__global__ void k_zero4(float4* p, int n4) {
    int i = blockIdx.x * blockDim.x + threadIdx.x;
    int stride = gridDim.x * blockDim.x;
    for (; i < n4; i += stride) p[i] = make_float4(0.f, 0.f, 0.f, 0.f);
}

// ---- ELL adjacency build ----
__global__ void k_ell_build(const int* __restrict__ ei, unsigned* __restrict__ cnt,
                            unsigned short* __restrict__ ell) {
    int e = blockIdx.x * blockDim.x + threadIdx.x;
    if (e >= E_TOT) return;
    int s, d; edge_sd(ei, e, s, d);
    unsigned slot = atomicAdd(&cnt[d], 1u);
    if (slot < MAX_DEG) ell[d * MAX_DEG + slot] = (unsigned short)s;
}

// ---- weight prep (parallel) ----
__global__ void k_wprep(const float* __restrict__ W1, const float* __restrict__ as1, const float* __restrict__ ad1,
                        const float* __restrict__ W2, const float* __restrict__ as2, const float* __restrict__ ad2,
                        const float* __restrict__ Wg1,
                        unsigned short* __restrict__ W1t, float* __restrict__ v1s, float* __restrict__ v1d,
                        unsigned short* __restrict__ W2t, float* __restrict__ v2s, float* __restrict__ v2d,
                        unsigned short* __restrict__ wg1h, unsigned short* __restrict__ wg1l) {
    int b = blockIdx.x, t = threadIdx.x;
    if (b < 32) {
        for (int i = b * 1024 + t; i < (b + 1) * 1024; i += 256) {
            int c = i >> 7, k = i & 127;
            W1t[i] = f2bf(W1[k * 256 + c]);
        }
    } else if (b < 48) {
        int bb = b - 32;
        for (int i = bb * 1024 + t; i < (bb + 1) * 1024; i += 256) {
            int c = i >> 8, k = i & 255;
            W2t[i] = f2bf(W2[k * 64 + c]);
        }
    } else if (b == 48) {
        for (int i = t; i < 512; i += 256) {
            int h = i >> 7, k = i & 127;
            float s = 0.f, d = 0.f;
            for (int c = 0; c < 64; ++c) {
                float wv = W1[k * 256 + h * 64 + c];
                s = fmaf(wv, as1[h * 64 + c], s);
                d = fmaf(wv, ad1[h * 64 + c], d);
            }
            v1s[i] = s; v1d[i] = d;
        }
    } else if (b == 49) {
        float s = 0.f, d = 0.f;
        for (int cc = 0; cc < 64; ++cc) {
            float wv = W2[t * 64 + cc];
            s = fmaf(wv, as2[cc], s);
            d = fmaf(wv, ad2[cc], d);
        }
        v2s[t] = s; v2d[t] = d;
    } else {
        for (int i = t; i < 4096; i += 256) {
            int c = i >> 6, k = i & 63;
            float v = Wg1[k * 64 + c];
            unsigned short h = f2bf(v);
            wg1h[i] = h;
            wg1l[i] = f2bf(v - bf2f(h));
        }
    }
}

// ---- layer 1 GEMM via MFMA + fused attention logit dots (wave w = head w) ----
__global__ __launch_bounds__(256)
void k_gemm1_mfma(const float* __restrict__ x, const unsigned short* __restrict__ W1t,
                  const float* __restrict__ v1s, const float* __restrict__ v1d,
                  unsigned short* __restrict__ h1b, float* __restrict__ a_src1,
                  float* __restrict__ a_dst1) {
    int w = threadIdx.x >> 6, l = threadIdx.x & 63;
    int r = l & 15, kg = l >> 4;
    int tile = blockIdx.x;
    const float* xr = x + (size_t)(tile * 16 + r) * 128 + kg * 8;
    bf16x8 af[4];
    float ps = 0.f, pd = 0.f;
    #pragma unroll
    for (int j = 0; j < 4; ++j) {
        float4 f0 = *(const float4*)(xr + j * 32);
        float4 f1 = *(const float4*)(xr + j * 32 + 4);
        const float* vs = v1s + w * 128 + j * 32 + kg * 8;
        const float* vd = v1d + w * 128 + j * 32 + kg * 8;
        float4 s0 = *(const float4*)vs, s1 = *(const float4*)(vs + 4);
        float4 d0 = *(const float4*)vd, d1 = *(const float4*)(vd + 4);
        ps += f0.x*s0.x + f0.y*s0.y + f0.z*s0.z + f0.w*s0.w
            + f1.x*s1.x + f1.y*s1.y + f1.z*s1.z + f1.w*s1.w;
        pd += f0.x*d0.x + f0.y*d0.y + f0.z*d0.z + f0.w*d0.w
            + f1.x*d1.x + f1.y*d1.y + f1.z*d1.z + f1.w*d1.w;
        bf16x8 t;
        t[0] = (short)f2bf(f0.x); t[1] = (short)f2bf(f0.y);
        t[2] = (short)f2bf(f0.z); t[3] = (short)f2bf(f0.w);
        t[4] = (short)f2bf(f1.x); t[5] = (short)f2bf(f1.y);
        t[6] = (short)f2bf(f1.z); t[7] = (short)f2bf(f1.w);
        af[j] = t;
    }
    ps += __shfl_xor(ps, 16); ps += __shfl_xor(ps, 32);
    pd += __shfl_xor(pd, 16); pd += __shfl_xor(pd, 32);
    if (l < 16) {
        a_src1[(size_t)(tile * 16 + r) * 4 + w] = ps;
        a_dst1[(size_t)(tile * 16 + r) * 4 + w] = pd;
    }
    for (int cc = 0; cc < 4; ++cc) {
        int c0 = cc * 64 + w * 16;
        const bf16x8* B = (const bf16x8*)(W1t + (size_t)(c0 + r) * 128 + kg * 8);
        f32x4 acc = {0.f, 0.f, 0.f, 0.f};
        acc = __builtin_amdgcn_mfma_f32_16x16x32_bf16(af[0], B[0],  acc, 0, 0, 0);
        acc = __builtin_amdgcn_mfma_f32_16x16x32_bf16(af[1], B[4],  acc, 0, 0, 0);
        acc = __builtin_amdgcn_mfma_f32_16x16x32_bf16(af[2], B[8],  acc, 0, 0, 0);
        acc = __builtin_amdgcn_mfma_f32_16x16x32_bf16(af[3], B[12], acc, 0, 0, 0);
        #pragma unroll
        for (int j = 0; j < 4; ++j)
            h1b[(size_t)(tile * 16 + kg * 4 + j) * 256 + c0 + r] = f2bf(acc[j]);
    }
}

// ---- FUSED layer 1: node gather+softmax+ELU (16 waves = 16 nodes) then gemm2 MFMA in-block ----
// sw is head-major [4][16][65]: writes stride-1 (conflict-free), pad 65 -> head reads alternate banks
__global__ __launch_bounds__(1024)
void k_layer1(const unsigned short* __restrict__ ell, const unsigned* __restrict__ cnt,
              const float4* __restrict__ asrc, const float4* __restrict__ adst,
              const unsigned short* __restrict__ h1b, const float4* __restrict__ bias,
              const float4* __restrict__ v2s4, const float4* __restrict__ v2d4,
              const unsigned short* __restrict__ W2t,
              float* __restrict__ a_src2, float* __restrict__ a_dst2,
              unsigned short* __restrict__ h2b) {
    __shared__ float sw[4][16][65];
    __shared__ int   ss[16][MAX_DEG];
    __shared__ unsigned short Ash[16][264];     // padded stride 528B
    int wave = threadIdx.x >> 6, lane = threadIdx.x & 63;
    int node = blockIdx.x * 16 + wave;
    int deg = min((int)cnt[node], MAX_DEG);

    float4 ad = adst[node];
    float a0 = -INFINITY, a1 = -INFINITY, a2 = -INFINITY, a3 = -INFINITY;
    int s = 0;
    if (lane < deg) {
        s = ell[node * MAX_DEG + lane];
        float4 as = asrc[s];
        a0 = leaky(as.x + ad.x); a1 = leaky(as.y + ad.y);
        a2 = leaky(as.z + ad.z); a3 = leaky(as.w + ad.w);
    }
    float m0 = a0, m1 = a1, m2 = a2, m3 = a3;
    for (int o = 32; o > 0; o >>= 1) {
        m0 = fmaxf(m0, __shfl_xor(m0, o)); m1 = fmaxf(m1, __shfl_xor(m1, o));
        m2 = fmaxf(m2, __shfl_xor(m2, o)); m3 = fmaxf(m3, __shfl_xor(m3, o));
    }
    float w0 = lane < deg ? expf(a0 - m0) : 0.f;
    float w1 = lane < deg ? expf(a1 - m1) : 0.f;
    float w2 = lane < deg ? expf(a2 - m2) : 0.f;
    float w3 = lane < deg ? expf(a3 - m3) : 0.f;
    float t0 = w0, t1 = w1, t2 = w2, t3 = w3;
    for (int o = 32; o > 0; o >>= 1) {
        t0 += __shfl_xor(t0, o); t1 += __shfl_xor(t1, o);
        t2 += __shfl_xor(t2, o); t3 += __shfl_xor(t3, o);
    }
    w0 /= (t0 + EPS); w1 /= (t1 + EPS); w2 /= (t2 + EPS); w3 /= (t3 + EPS);
    if (lane < deg) {
        sw[0][wave][lane] = w0; sw[1][wave][lane] = w1;
        sw[2][wave][lane] = w2; sw[3][wave][lane] = w3;
        ss[wave][lane] = s;
    }
    // wave-private LDS write->read; in-wave ordering via lgkmcnt
    int head = lane >> 4;
    float c0 = 0.f, c1 = 0.f, c2 = 0.f, c3 = 0.f;
    for (int e = 0; e < deg; ++e) {
        int se = ss[wave][e];
        float w = sw[head][wave][e];
        ushort4 h = *(const ushort4*)(h1b + (size_t)se * 256 + lane * 4);
        c0 = fmaf(bf2f(h.x), w, c0); c1 = fmaf(bf2f(h.y), w, c1);
        c2 = fmaf(bf2f(h.z), w, c2); c3 = fmaf(bf2f(h.w), w, c3);
    }
    float4 b = bias[lane];
    float o0 = elu(c0 + b.x), o1 = elu(c1 + b.y), o2 = elu(c2 + b.z), o3 = elu(c3 + b.w);
    *(ushort4*)&Ash[wave][lane * 4] = make_ushort4(f2bf(o0), f2bf(o1), f2bf(o2), f2bf(o3));
    // layer-2 logits in exact f32 from registers
    float4 vs = v2s4[lane], vd = v2d4[lane];
    float ps = o0 * vs.x + o1 * vs.y + o2 * vs.z + o3 * vs.w;
    float pd = o0 * vd.x + o1 * vd.y + o2 * vd.z + o3 * vd.w;
    for (int o = 32; o > 0; o >>= 1) { ps += __shfl_xor(ps, o); pd += __shfl_xor(pd, o); }
    if (lane == 0) { a_src2[node] = ps; a_dst2[node] = pd; }

    __syncthreads();
    // phase B: gemm2 for this 16-node tile (waves 0-3, col-tiles of 16)
    if (wave < 4) {
        int r = lane & 15, kg = lane >> 4;
        f32x4 acc = {0.f, 0.f, 0.f, 0.f};
        #pragma unroll
        for (int kk = 0; kk < 8; ++kk) {
            bf16x8 afr = *(const bf16x8*)&Ash[r][kg * 8 + kk * 32];
            bf16x8 bfr = *(const bf16x8*)(W2t + (size_t)(wave * 16 + r) * 256 + kg * 8 + kk * 32);
            acc = __builtin_amdgcn_mfma_f32_16x16x32_bf16(afr, bfr, acc, 0, 0, 0);
        }
        #pragma unroll
        for (int j = 0; j < 4; ++j)
            h2b[(size_t)(blockIdx.x * 16 + kg * 4 + j) * 64 + wave * 16 + r] = f2bf(acc[j]);
    }
}

// ---- FUSED layer 2: node gather (H=1) then gate MFMA in-block ----
__global__ __launch_bounds__(1024)
void k_layer2(const unsigned short* __restrict__ ell, const unsigned* __restrict__ cnt,
              const float* __restrict__ asrc, const float* __restrict__ adst,
              const unsigned short* __restrict__ h2b, const float* __restrict__ bias,
              const unsigned short* __restrict__ wg1h, const unsigned short* __restrict__ wg1l,
              const float* __restrict__ bg1, const float* __restrict__ Wg2,
              const float* __restrict__ bg2,
              float* __restrict__ out2, float* __restrict__ gate) {
    __shared__ float sw[16][MAX_DEG];
    __shared__ int   ss[16][MAX_DEG];
    __shared__ unsigned short Ah[16][72], Al[16][72];  // padded stride 144B
    __shared__ float gp[4][16];
    int wave = threadIdx.x >> 6, lane = threadIdx.x & 63;
    int half = lane >> 5, li = lane & 31;
    int node = blockIdx.x * 16 + wave;
    int deg = min((int)cnt[node], MAX_DEG);

    float adv = adst[node];
    float a = -INFINITY;
    int s = 0;
    if (lane < deg) {
        s = ell[node * MAX_DEG + lane];
        a = leaky(asrc[s] + adv);
    }
    float m = a;
    for (int o = 32; o > 0; o >>= 1) m = fmaxf(m, __shfl_xor(m, o));
    float w = lane < deg ? expf(a - m) : 0.f;
    float t = w;
    for (int o = 32; o > 0; o >>= 1) t += __shfl_xor(t, o);
    w /= (t + EPS);
    if (lane < deg) { sw[wave][lane] = w; ss[wave][lane] = s; }

    float c0 = 0.f, c1 = 0.f;
    for (int e = 0; e < deg; e += 2) {
        int row = e + half;
        if (row < deg) {
            int se = ss[wave][row];
            float ww = sw[wave][row];
            unsigned u = *(const unsigned*)(h2b + (size_t)se * 64 + li * 2);
            c0 = fmaf(__uint_as_float(u << 16), ww, c0);
            c1 = fmaf(__uint_as_float(u & 0xffff0000u), ww, c1);
        }
    }
    c0 += __shfl_xor(c0, 32);
    c1 += __shfl_xor(c1, 32);
    if (half == 0) {
        float o0 = elu(c0 + bias[li * 2]);
        float o1 = elu(c1 + bias[li * 2 + 1]);
        *(float2*)(out2 + (size_t)node * 64 + li * 2) = make_float2(o0, o1);
        unsigned short h0 = f2bf(o0), h1 = f2bf(o1);
        *(unsigned*)&Ah[wave][li * 2] = ((unsigned)h1 << 16) | h0;
        unsigned short l0 = f2bf(o0 - bf2f(h0)), l1 = f2bf(o1 - bf2f(h1));
        *(unsigned*)&Al[wave][li * 2] = ((unsigned)l1 << 16) | l0;
    }

    __syncthreads();
    // phase B: gate MLP for this 16-node tile (waves 0-3)
    if (wave < 4) {
        int r = lane & 15, kg = lane >> 4;
        const bf16x8* Bh = (const bf16x8*)(wg1h + (size_t)(wave * 16 + r) * 64 + kg * 8);
        const bf16x8* Bl = (const bf16x8*)(wg1l + (size_t)(wave * 16 + r) * 64 + kg * 8);
        bf16x8 ah0 = *(const bf16x8*)&Ah[r][kg * 8];
        bf16x8 ah1 = *(const bf16x8*)&Ah[r][kg * 8 + 32];
        bf16x8 al0 = *(const bf16x8*)&Al[r][kg * 8];
        bf16x8 al1 = *(const bf16x8*)&Al[r][kg * 8 + 32];
        f32x4 acc = {0.f, 0.f, 0.f, 0.f};
        acc = __builtin_amdgcn_mfma_f32_16x16x32_bf16(ah0, Bh[0], acc, 0, 0, 0);
        acc = __builtin_amdgcn_mfma_f32_16x16x32_bf16(ah1, Bh[4], acc, 0, 0, 0);
        acc = __builtin_amdgcn_mfma_f32_16x16x32_bf16(ah0, Bl[0], acc, 0, 0, 0);
        acc = __builtin_amdgcn_mfma_f32_16x16x32_bf16(ah1, Bl[4], acc, 0, 0, 0);
        acc = __builtin_amdgcn_mfma_f32_16x16x32_bf16(al0, Bh[0], acc, 0, 0, 0);
        acc = __builtin_amdgcn_mfma_f32_16x16x32_bf16(al1, Bh[4], acc, 0, 0, 0);
        int col = wave * 16 + r;
        float wg2 = Wg2[col], bb = bg1[col];
        float part[4];
        #pragma unroll
        for (int j = 0; j < 4; ++j) part[j] = fmaxf(acc[j] + bb, 0.f) * wg2;
        #pragma unroll
        for (int o = 8; o > 0; o >>= 1) {
            #pragma unroll
            for (int j = 0; j < 4; ++j) part[j] += __shfl_xor(part[j], o);
        }
        if (r == 0) {
            #pragma unroll
            for (int j = 0; j < 4; ++j) gp[wave][kg * 4 + j] = part[j];
        }
    }
    __syncthreads();
    if (threadIdx.x < 16)
        gate[blockIdx.x * 16 + threadIdx.x] = gp[0][threadIdx.x] + gp[1][threadIdx.x]
                                            + gp[2][threadIdx.x] + gp[3][threadIdx.x] + bg2[0];
}

// ---- per-graph softmax + weighted aggregation (1024 threads) ----
__global__ __launch_bounds__(1024)
void k_final(const float* __restrict__ gate, const float* __restrict__ hfin,
             const int* __restrict__ batch, float* __restrict__ out) {
    __shared__ float red[16];
    __shared__ float redc[16][64];
    int g = blockIdx.x;
    int lo = lbound(batch, N_NODES, g);
    int hi = lbound(batch, N_NODES, g + 1);
    int tid = threadIdx.x, wave = tid >> 6, lane = tid & 63;

    float m = -INFINITY;
    for (int i = lo + tid; i < hi; i += 1024) m = fmaxf(m, gate[i]);
    for (int o = 32; o > 0; o >>= 1) m = fmaxf(m, __shfl_xor(m, o));
    if (lane == 0) red[wave] = m;
    __syncthreads();
    m = -INFINITY;
    #pragma unroll
    for (int i = 0; i < 16; ++i) m = fmaxf(m, red[i]);
    __syncthreads();

    float s = 0.f;
    for (int i = lo + tid; i < hi; i += 1024) s += expf(gate[i] - m);
    for (int o = 32; o > 0; o >>= 1) s += __shfl_xor(s, o);
    if (lane == 0) red[wave] = s;
    __syncthreads();
    s = 0.f;
    #pragma unroll
    for (int i = 0; i < 16; ++i) s += red[i];

    float acc = 0.f;
    for (int i = lo + wave; i < hi; i += 16)
        acc = fmaf(expf(gate[i] - m), hfin[(size_t)i * 64 + lane], acc);
    redc[wave][lane] = acc;
    __syncthreads();
    if (tid < 64) {
        float r = 0.f;
        #pragma unroll
        for (int i = 0; i < 16; ++i) r += redc[i][tid];
        out[g * 64 + tid] = r / (s + EPS);
    }
}

extern "C" void kernel_launch(void* const* d_in, const int* in_sizes, int n_in,
                              void* d_out, int out_size, void* d_ws, size_t ws_size,
                              hipStream_t stream) {
    const float* x    = (const float*)d_in[0];
    const int*   ei   = (const int*)d_in[1];
    const int*   batch= (const int*)d_in[2];
    const float* W1   = (const float*)d_in[3];
    const float* as1  = (const float*)d_in[4];
    const float* ad1  = (const float*)d_in[5];
    const float* b1   = (const float*)d_in[6];
    const float* W2   = (const float*)d_in[7];
    const float* as2  = (const float*)d_in[8];
    const float* ad2  = (const float*)d_in[9];
    const float* b2   = (const float*)d_in[10];
    const float* Wg1  = (const float*)d_in[11];
    const float* bg1  = (const float*)d_in[12];
    const float* Wg2  = (const float*)d_in[13];
    const float* bg2  = (const float*)d_in[14];
    float* out = (float*)d_out;

    char* W = (char*)d_ws;
    size_t off = 0;
    // ---- zeroed region: cnt only ----
    unsigned* cnt = (unsigned*)(W + off); off += (size_t)N_NODES * 4;
    size_t zero_bytes = off;
    // ---- write-before-read (16B aligned) ----
    unsigned short* ell  = (unsigned short*)(W + off); off += (size_t)N_NODES * MAX_DEG * 2; // 6.4 MB
    unsigned short* h1b  = (unsigned short*)(W + off); size_t h1_off = off;
    off += (size_t)N_NODES * 256 * 2;                                                        // 25.6 MB
    float* a_src1 = (float*)(W + off); off += (size_t)N_NODES * HEADS * 4;
    float* a_dst1 = (float*)(W + off); off += (size_t)N_NODES * HEADS * 4;
    float* a_src2 = (float*)(W + off); off += (size_t)N_NODES * 4;
    float* a_dst2 = (float*)(W + off); off += (size_t)N_NODES * 4;
    float* out2   = (float*)(W + off); off += (size_t)N_NODES * HID * 4;                     // 12.8 MB
    float* gate   = (float*)(W + off); off += (size_t)N_NODES * 4;
    unsigned short* W1t = (unsigned short*)(W + off); off += (size_t)128 * 256 * 2;
    float* v1s = (float*)(W + off); off += 512 * 4;
    float* v1d = (float*)(W + off); off += 512 * 4;
    unsigned short* W2t = (unsigned short*)(W + off); off += (size_t)64 * 256 * 2;
    float* v2s = (float*)(W + off); off += 256 * 4;
    float* v2d = (float*)(W + off); off += 256 * 4;
    unsigned short* wg1h = (unsigned short*)(W + off); off += (size_t)64 * 64 * 2;
    unsigned short* wg1l = (unsigned short*)(W + off); off += (size_t)64 * 64 * 2;
    unsigned short* h2b = (unsigned short*)(W + off); off += (size_t)N_NODES * HID * 2;      // 6.4 MB
    (void)h1_off; (void)ws_size; (void)in_sizes; (void)n_in; (void)out_size;

    k_zero4<<<64, 256, 0, stream>>>((float4*)W, (int)(zero_bytes / 16));
    k_ell_build<<<(E_TOT + 255) / 256, 256, 0, stream>>>(ei, cnt, ell);
    k_wprep<<<51, 256, 0, stream>>>(W1, as1, ad1, W2, as2, ad2, Wg1,
                                    W1t, v1s, v1d, W2t, v2s, v2d, wg1h, wg1l);

    // layer 1 GEMM (+ logit dots)
    k_gemm1_mfma<<<N_NODES / 16, 256, 0, stream>>>(x, W1t, v1s, v1d, h1b, a_src1, a_dst1);
    // fused: node1 gather + gemm2
    k_layer1<<<N_NODES / 16, 1024, 0, stream>>>(ell, cnt, (const float4*)a_src1,
        (const float4*)a_dst1, h1b, (const float4*)b1,
        (const float4*)v2s, (const float4*)v2d, W2t, a_src2, a_dst2, h2b);
    // fused: node2 gather + gate MLP
    k_layer2<<<N_NODES / 16, 1024, 0, stream>>>(ell, cnt, a_src2, a_dst2, h2b, b2,
                                                wg1h, wg1l, bg1, Wg2, bg2, out2, gate);
    // per-graph softmax aggregation
    k_final<<<N_GRAPHS, 1024, 0, stream>>>(gate, out2, batch, out);
}

// Round 14
// 282.559 us; speedup vs baseline: 1.3387x; 1.0211x over previous
//
#include <hip/hip_runtime.h>
#include <math.h>

#define N_NODES 50000
#define N_EDGES 800000
#define E_TOT   850000   // + self loops
#define N_GRAPHS 64
#define EMB 128
#define HID 64
#define HEADS 4
#define NEG_SLOPE 0.2f
#define EPS 1e-16f
#define MAX_DEG 64
#define G1_TILES (N_NODES / 16)   // 3125 gemm1 tiles
#define ELL_BLKS ((E_TOT + 255) / 256)

typedef short bf16x8 __attribute__((ext_vector_type(8)));
typedef float f32x4  __attribute__((ext_vector_type(4)));

__device__ __forceinline__ float leaky(float x) { return x >= 0.f ? x : NEG_SLOPE * x; }
__device__ __forceinline__ float elu(float x)   { return x > 0.f ? x : expf(x) - 1.f; }

__device__ __forceinline__ unsigned short f2bf(float f) {
    unsigned u = __float_as_uint(f);
    return (unsigned short)((u + 0x7FFFu + ((u >> 16) & 1u)) >> 16);
}
__device__ __forceinline__ float bf2f(unsigned short h) {
    return __uint_as_float((unsigned)h << 16);
}

__device__ __forceinline__ void edge_sd(const int* __restrict__ ei, int e, int& s, int& d) {
    if (e < N_EDGES) { s = ei[e]; d = ei[N_EDGES + e]; }
    else             { s = d = e - N_EDGES; }
}

__device__ __forceinline__ int lbound(const int* __restrict__ a, int n, int v) {
    int lo = 0, hi = n;
    while (lo < hi) { int mid = (lo + hi) >> 1; if (a[mid] < v) lo = mid + 1; else hi = mid; }
    return lo;
}

// ---- weight prep + cnt zero (blocks 51-63) ----
__global__ void k_wprep(const float* __restrict__ W1, const float* __restrict__ as1, const float* __restrict__ ad1,
                        const float* __restrict__ W2, const float* __restrict__ as2, const float* __restrict__ ad2,
                        const float* __restrict__ Wg1,
                        unsigned short* __restrict__ W1t, float* __restrict__ v1s, float* __restrict__ v1d,
                        unsigned short* __restrict__ W2t, float* __restrict__ v2s, float* __restrict__ v2d,
                        unsigned short* __restrict__ wg1h, unsigned short* __restrict__ wg1l,
                        unsigned* __restrict__ cnt) {
    int b = blockIdx.x, t = threadIdx.x;
    if (b < 32) {
        for (int i = b * 1024 + t; i < (b + 1) * 1024; i += 256) {
            int c = i >> 7, k = i & 127;
            W1t[i] = f2bf(W1[k * 256 + c]);
        }
    } else if (b < 48) {
        int bb = b - 32;
        for (int i = bb * 1024 + t; i < (bb + 1) * 1024; i += 256) {
            int c = i >> 8, k = i & 255;
            W2t[i] = f2bf(W2[k * 64 + c]);
        }
    } else if (b == 48) {
        for (int i = t; i < 512; i += 256) {
            int h = i >> 7, k = i & 127;
            float s = 0.f, d = 0.f;
            for (int c = 0; c < 64; ++c) {
                float wv = W1[k * 256 + h * 64 + c];
                s = fmaf(wv, as1[h * 64 + c], s);
                d = fmaf(wv, ad1[h * 64 + c], d);
            }
            v1s[i] = s; v1d[i] = d;
        }
    } else if (b == 49) {
        float s = 0.f, d = 0.f;
        for (int cc = 0; cc < 64; ++cc) {
            float wv = W2[t * 64 + cc];
            s = fmaf(wv, as2[cc], s);
            d = fmaf(wv, ad2[cc], d);
        }
        v2s[t] = s; v2d[t] = d;
    } else if (b == 50) {
        for (int i = t; i < 4096; i += 256) {
            int c = i >> 6, k = i & 63;
            float v = Wg1[k * 64 + c];
            unsigned short h = f2bf(v);
            wg1h[i] = h;
            wg1l[i] = f2bf(v - bf2f(h));
        }
    } else {                                        // blocks 51-63: zero cnt
        for (int i = (b - 51) * 256 + t; i < N_NODES; i += 13 * 256) cnt[i] = 0;
    }
}

// ---- FUSED: gemm1 MFMA (+logit dots) [blocks 0..3124] | ELL build [blocks 3125..] ----
__global__ __launch_bounds__(256)
void k_prep2(const float* __restrict__ x, const unsigned short* __restrict__ W1t,
             const float* __restrict__ v1s, const float* __restrict__ v1d,
             unsigned short* __restrict__ h1b, float* __restrict__ a_src1,
             float* __restrict__ a_dst1,
             const int* __restrict__ ei, unsigned* __restrict__ cnt,
             unsigned short* __restrict__ ell) {
    if (blockIdx.x >= G1_TILES) {
        int e = (blockIdx.x - G1_TILES) * 256 + threadIdx.x;
        if (e < E_TOT) {
            int s, d; edge_sd(ei, e, s, d);
            unsigned slot = atomicAdd(&cnt[d], 1u);
            if (slot < MAX_DEG) ell[d * MAX_DEG + slot] = (unsigned short)s;
        }
        return;
    }
    int w = threadIdx.x >> 6, l = threadIdx.x & 63;
    int r = l & 15, kg = l >> 4;
    int tile = blockIdx.x;
    const float* xr = x + (size_t)(tile * 16 + r) * 128 + kg * 8;
    bf16x8 af[4];
    float ps = 0.f, pd = 0.f;
    #pragma unroll
    for (int j = 0; j < 4; ++j) {
        float4 f0 = *(const float4*)(xr + j * 32);
        float4 f1 = *(const float4*)(xr + j * 32 + 4);
        const float* vs = v1s + w * 128 + j * 32 + kg * 8;
        const float* vd = v1d + w * 128 + j * 32 + kg * 8;
        float4 s0 = *(const float4*)vs, s1 = *(const float4*)(vs + 4);
        float4 d0 = *(const float4*)vd, d1 = *(const float4*)(vd + 4);
        ps += f0.x*s0.x + f0.y*s0.y + f0.z*s0.z + f0.w*s0.w
            + f1.x*s1.x + f1.y*s1.y + f1.z*s1.z + f1.w*s1.w;
        pd += f0.x*d0.x + f0.y*d0.y + f0.z*d0.z + f0.w*d0.w
            + f1.x*d1.x + f1.y*d1.y + f1.z*d1.z + f1.w*d1.w;
        bf16x8 t;
        t[0] = (short)f2bf(f0.x); t[1] = (short)f2bf(f0.y);
        t[2] = (short)f2bf(f0.z); t[3] = (short)f2bf(f0.w);
        t[4] = (short)f2bf(f1.x); t[5] = (short)f2bf(f1.y);
        t[6] = (short)f2bf(f1.z); t[7] = (short)f2bf(f1.w);
        af[j] = t;
    }
    ps += __shfl_xor(ps, 16); ps += __shfl_xor(ps, 32);
    pd += __shfl_xor(pd, 16); pd += __shfl_xor(pd, 32);
    if (l < 16) {
        a_src1[(size_t)(tile * 16 + r) * 4 + w] = ps;
        a_dst1[(size_t)(tile * 16 + r) * 4 + w] = pd;
    }
    for (int cc = 0; cc < 4; ++cc) {
        int c0 = cc * 64 + w * 16;
        const bf16x8* B = (const bf16x8*)(W1t + (size_t)(c0 + r) * 128 + kg * 8);
        f32x4 acc = {0.f, 0.f, 0.f, 0.f};
        acc = __builtin_amdgcn_mfma_f32_16x16x32_bf16(af[0], B[0],  acc, 0, 0, 0);
        acc = __builtin_amdgcn_mfma_f32_16x16x32_bf16(af[1], B[4],  acc, 0, 0, 0);
        acc = __builtin_amdgcn_mfma_f32_16x16x32_bf16(af[2], B[8],  acc, 0, 0, 0);
        acc = __builtin_amdgcn_mfma_f32_16x16x32_bf16(af[3], B[12], acc, 0, 0, 0);
        #pragma unroll
        for (int j = 0; j < 4; ++j)
            h1b[(size_t)(tile * 16 + kg * 4 + j) * 256 + c0 + r] = f2bf(acc[j]);
    }
}

// ---- FUSED layer 1: node gather (pipelined) + softmax + ELU, then gemm2 MFMA in-block ----
__global__ __launch_bounds__(1024)
void k_layer1(const unsigned short* __restrict__ ell, const unsigned* __restrict__ cnt,
              const float4* __restrict__ asrc, const float4* __restrict__ adst,
              const unsigned short* __restrict__ h1b, const float4* __restrict__ bias,
              const float4* __restrict__ v2s4, const float4* __restrict__ v2d4,
              const unsigned short* __restrict__ W2t,
              float* __restrict__ a_src2, float* __restrict__ a_dst2,
              unsigned short* __restrict__ h2b) {
    __shared__ float sw[4][16][65];
    __shared__ int   ss[16][MAX_DEG];
    __shared__ unsigned short Ash[16][264];
    int wave = threadIdx.x >> 6, lane = threadIdx.x & 63;
    int node = blockIdx.x * 16 + wave;
    int deg = min((int)cnt[node], MAX_DEG);

    float4 ad = adst[node];
    float a0 = -INFINITY, a1 = -INFINITY, a2 = -INFINITY, a3 = -INFINITY;
    int s = 0;
    if (lane < deg) {
        s = ell[node * MAX_DEG + lane];
        float4 as = asrc[s];
        a0 = leaky(as.x + ad.x); a1 = leaky(as.y + ad.y);
        a2 = leaky(as.z + ad.z); a3 = leaky(as.w + ad.w);
    }
    float m0 = a0, m1 = a1, m2 = a2, m3 = a3;
    for (int o = 32; o > 0; o >>= 1) {
        m0 = fmaxf(m0, __shfl_xor(m0, o)); m1 = fmaxf(m1, __shfl_xor(m1, o));
        m2 = fmaxf(m2, __shfl_xor(m2, o)); m3 = fmaxf(m3, __shfl_xor(m3, o));
    }
    float w0 = lane < deg ? expf(a0 - m0) : 0.f;
    float w1 = lane < deg ? expf(a1 - m1) : 0.f;
    float w2 = lane < deg ? expf(a2 - m2) : 0.f;
    float w3 = lane < deg ? expf(a3 - m3) : 0.f;
    float t0 = w0, t1 = w1, t2 = w2, t3 = w3;
    for (int o = 32; o > 0; o >>= 1) {
        t0 += __shfl_xor(t0, o); t1 += __shfl_xor(t1, o);
        t2 += __shfl_xor(t2, o); t3 += __shfl_xor(t3, o);
    }
    w0 /= (t0 + EPS); w1 /= (t1 + EPS); w2 /= (t2 + EPS); w3 /= (t3 + EPS);
    if (lane < deg) {
        sw[0][wave][lane] = w0; sw[1][wave][lane] = w1;
        sw[2][wave][lane] = w2; sw[3][wave][lane] = w3;
        ss[wave][lane] = s;
    }
    // wave-private LDS write->read; in-wave ordering via lgkmcnt
    int head = lane >> 4;
    float c0 = 0.f, c1 = 0.f, c2 = 0.f, c3 = 0.f;
    // 1-deep software pipeline: issue load e+1 before consuming row e (deg>=1: self-loop)
    ushort4 hcur = *(const ushort4*)(h1b + (size_t)ss[wave][0] * 256 + lane * 4);
    float   wcur = sw[head][wave][0];
    for (int e = 1; e < deg; ++e) {
        ushort4 hnx = *(const ushort4*)(h1b + (size_t)ss[wave][e] * 256 + lane * 4);
        float   wnx = sw[head][wave][e];
        c0 = fmaf(bf2f(hcur.x), wcur, c0); c1 = fmaf(bf2f(hcur.y), wcur, c1);
        c2 = fmaf(bf2f(hcur.z), wcur, c2); c3 = fmaf(bf2f(hcur.w), wcur, c3);
        hcur = hnx; wcur = wnx;
    }
    c0 = fmaf(bf2f(hcur.x), wcur, c0); c1 = fmaf(bf2f(hcur.y), wcur, c1);
    c2 = fmaf(bf2f(hcur.z), wcur, c2); c3 = fmaf(bf2f(hcur.w), wcur, c3);

    float4 b = bias[lane];
    float o0 = elu(c0 + b.x), o1 = elu(c1 + b.y), o2 = elu(c2 + b.z), o3 = elu(c3 + b.w);
    *(ushort4*)&Ash[wave][lane * 4] = make_ushort4(f2bf(o0), f2bf(o1), f2bf(o2), f2bf(o3));
    float4 vs = v2s4[lane], vd = v2d4[lane];
    float ps = o0 * vs.x + o1 * vs.y + o2 * vs.z + o3 * vs.w;
    float pd = o0 * vd.x + o1 * vd.y + o2 * vd.z + o3 * vd.w;
    for (int o = 32; o > 0; o >>= 1) { ps += __shfl_xor(ps, o); pd += __shfl_xor(pd, o); }
    if (lane == 0) { a_src2[node] = ps; a_dst2[node] = pd; }

    __syncthreads();
    if (wave < 4) {
        int r = lane & 15, kg = lane >> 4;
        f32x4 acc = {0.f, 0.f, 0.f, 0.f};
        #pragma unroll
        for (int kk = 0; kk < 8; ++kk) {
            bf16x8 afr = *(const bf16x8*)&Ash[r][kg * 8 + kk * 32];
            bf16x8 bfr = *(const bf16x8*)(W2t + (size_t)(wave * 16 + r) * 256 + kg * 8 + kk * 32);
            acc = __builtin_amdgcn_mfma_f32_16x16x32_bf16(afr, bfr, acc, 0, 0, 0);
        }
        #pragma unroll
        for (int j = 0; j < 4; ++j)
            h2b[(size_t)(blockIdx.x * 16 + kg * 4 + j) * 64 + wave * 16 + r] = f2bf(acc[j]);
    }
}

// ---- FUSED layer 2: node gather (pipelined) + gate MFMA in-block ----
__global__ __launch_bounds__(1024)
void k_layer2(const unsigned short* __restrict__ ell, const unsigned* __restrict__ cnt,
              const float* __restrict__ asrc, const float* __restrict__ adst,
              const unsigned short* __restrict__ h2b, const float* __restrict__ bias,
              const unsigned short* __restrict__ wg1h, const unsigned short* __restrict__ wg1l,
              const float* __restrict__ bg1, const float* __restrict__ Wg2,
              const float* __restrict__ bg2,
              float* __restrict__ out2, float* __restrict__ gate) {
    __shared__ float sw[16][MAX_DEG];
    __shared__ int   ss[16][MAX_DEG];
    __shared__ unsigned short Ah[16][72], Al[16][72];
    __shared__ float gp[4][16];
    int wave = threadIdx.x >> 6, lane = threadIdx.x & 63;
    int half = lane >> 5, li = lane & 31;
    int node = blockIdx.x * 16 + wave;
    int deg = min((int)cnt[node], MAX_DEG);

    float adv = adst[node];
    float a = -INFINITY;
    int s = 0;
    if (lane < deg) {
        s = ell[node * MAX_DEG + lane];
        a = leaky(asrc[s] + adv);
    }
    float m = a;
    for (int o = 32; o > 0; o >>= 1) m = fmaxf(m, __shfl_xor(m, o));
    float w = lane < deg ? expf(a - m) : 0.f;
    float t = w;
    for (int o = 32; o > 0; o >>= 1) t += __shfl_xor(t, o);
    w /= (t + EPS);
    if (lane < deg) { sw[wave][lane] = w; ss[wave][lane] = s; }

    // pipelined: lanes split into 2 halves, each walks rows half, half+2, ...
    float c0 = 0.f, c1 = 0.f;
    int row = half;
    unsigned ucur = 0; float wcur = 0.f;
    if (row < deg) {
        ucur = *(const unsigned*)(h2b + (size_t)ss[wave][row] * 64 + li * 2);
        wcur = sw[wave][row];
    }
    while (row < deg) {
        int nrow = row + 2;
        unsigned unx = 0; float wnx = 0.f;
        if (nrow < deg) {
            unx = *(const unsigned*)(h2b + (size_t)ss[wave][nrow] * 64 + li * 2);
            wnx = sw[wave][nrow];
        }
        c0 = fmaf(__uint_as_float(ucur << 16), wcur, c0);
        c1 = fmaf(__uint_as_float(ucur & 0xffff0000u), wcur, c1);
        ucur = unx; wcur = wnx; row = nrow;
    }
    c0 += __shfl_xor(c0, 32);
    c1 += __shfl_xor(c1, 32);
    if (half == 0) {
        float o0 = elu(c0 + bias[li * 2]);
        float o1 = elu(c1 + bias[li * 2 + 1]);
        *(float2*)(out2 + (size_t)node * 64 + li * 2) = make_float2(o0, o1);
        unsigned short h0 = f2bf(o0), h1 = f2bf(o1);
        *(unsigned*)&Ah[wave][li * 2] = ((unsigned)h1 << 16) | h0;
        unsigned short l0 = f2bf(o0 - bf2f(h0)), l1 = f2bf(o1 - bf2f(h1));
        *(unsigned*)&Al[wave][li * 2] = ((unsigned)l1 << 16) | l0;
    }

    __syncthreads();
    if (wave < 4) {
        int r = lane & 15, kg = lane >> 4;
        const bf16x8* Bh = (const bf16x8*)(wg1h + (size_t)(wave * 16 + r) * 64 + kg * 8);
        const bf16x8* Bl = (const bf16x8*)(wg1l + (size_t)(wave * 16 + r) * 64 + kg * 8);
        bf16x8 ah0 = *(const bf16x8*)&Ah[r][kg * 8];
        bf16x8 ah1 = *(const bf16x8*)&Ah[r][kg * 8 + 32];
        bf16x8 al0 = *(const bf16x8*)&Al[r][kg * 8];
        bf16x8 al1 = *(const bf16x8*)&Al[r][kg * 8 + 32];
        f32x4 acc = {0.f, 0.f, 0.f, 0.f};
        acc = __builtin_amdgcn_mfma_f32_16x16x32_bf16(ah0, Bh[0], acc, 0, 0, 0);
        acc = __builtin_amdgcn_mfma_f32_16x16x32_bf16(ah1, Bh[4], acc, 0, 0, 0);
        acc = __builtin_amdgcn_mfma_f32_16x16x32_bf16(ah0, Bl[0], acc, 0, 0, 0);
        acc = __builtin_amdgcn_mfma_f32_16x16x32_bf16(ah1, Bl[4], acc, 0, 0, 0);
        acc = __builtin_amdgcn_mfma_f32_16x16x32_bf16(al0, Bh[0], acc, 0, 0, 0);
        acc = __builtin_amdgcn_mfma_f32_16x16x32_bf16(al1, Bh[4], acc, 0, 0, 0);
        int col = wave * 16 + r;
        float wg2 = Wg2[col], bb = bg1[col];
        float part[4];
        #pragma unroll
        for (int j = 0; j < 4; ++j) part[j] = fmaxf(acc[j] + bb, 0.f) * wg2;
        #pragma unroll
        for (int o = 8; o > 0; o >>= 1) {
            #pragma unroll
            for (int j = 0; j < 4; ++j) part[j] += __shfl_xor(part[j], o);
        }
        if (r == 0) {
            #pragma unroll
            for (int j = 0; j < 4; ++j) gp[wave][kg * 4 + j] = part[j];
        }
    }
    __syncthreads();
    if (threadIdx.x < 16)
        gate[blockIdx.x * 16 + threadIdx.x] = gp[0][threadIdx.x] + gp[1][threadIdx.x]
                                            + gp[2][threadIdx.x] + gp[3][threadIdx.x] + bg2[0];
}

// ---- per-graph softmax + weighted aggregation (1024 threads) ----
__global__ __launch_bounds__(1024)
void k_final(const float* __restrict__ gate, const float* __restrict__ hfin,
             const int* __restrict__ batch, float* __restrict__ out) {
    __shared__ float red[16];
    __shared__ float redc[16][64];
    int g = blockIdx.x;
    int lo = lbound(batch, N_NODES, g);
    int hi = lbound(batch, N_NODES, g + 1);
    int tid = threadIdx.x, wave = tid >> 6, lane = tid & 63;

    float m = -INFINITY;
    for (int i = lo + tid; i < hi; i += 1024) m = fmaxf(m, gate[i]);
    for (int o = 32; o > 0; o >>= 1) m = fmaxf(m, __shfl_xor(m, o));
    if (lane == 0) red[wave] = m;
    __syncthreads();
    m = -INFINITY;
    #pragma unroll
    for (int i = 0; i < 16; ++i) m = fmaxf(m, red[i]);
    __syncthreads();

    float s = 0.f;
    for (int i = lo + tid; i < hi; i += 1024) s += expf(gate[i] - m);
    for (int o = 32; o > 0; o >>= 1) s += __shfl_xor(s, o);
    if (lane == 0) red[wave] = s;
    __syncthreads();
    s = 0.f;
    #pragma unroll
    for (int i = 0; i < 16; ++i) s += red[i];

    float acc = 0.f;
    for (int i = lo + wave; i < hi; i += 16)
        acc = fmaf(expf(gate[i] - m), hfin[(size_t)i * 64 + lane], acc);
    redc[wave][lane] = acc;
    __syncthreads();
    if (tid < 64) {
        float r = 0.f;
        #pragma unroll
        for (int i = 0; i < 16; ++i) r += redc[i][tid];
        out[g * 64 + tid] = r / (s + EPS);
    }
}

extern "C" void kernel_launch(void* const* d_in, const int* in_sizes, int n_in,
                              void* d_out, int out_size, void* d_ws, size_t ws_size,
                              hipStream_t stream) {
    const float* x    = (const float*)d_in[0];
    const int*   ei   = (const int*)d_in[1];
    const int*   batch= (const int*)d_in[2];
    const float* W1   = (const float*)d_in[3];
    const float* as1  = (const float*)d_in[4];
    const float* ad1  = (const float*)d_in[5];
    const float* b1   = (const float*)d_in[6];
    const float* W2   = (const float*)d_in[7];
    const float* as2  = (const float*)d_in[8];
    const float* ad2  = (const float*)d_in[9];
    const float* b2   = (const float*)d_in[10];
    const float* Wg1  = (const float*)d_in[11];
    const float* bg1  = (const float*)d_in[12];
    const float* Wg2  = (const float*)d_in[13];
    const float* bg2  = (const float*)d_in[14];
    float* out = (float*)d_out;

    char* W = (char*)d_ws;
    size_t off = 0;
    unsigned* cnt = (unsigned*)(W + off); off += (size_t)N_NODES * 4;
    unsigned short* ell  = (unsigned short*)(W + off); off += (size_t)N_NODES * MAX_DEG * 2; // 6.4 MB
    unsigned short* h1b  = (unsigned short*)(W + off); off += (size_t)N_NODES * 256 * 2;     // 25.6 MB
    float* a_src1 = (float*)(W + off); off += (size_t)N_NODES * HEADS * 4;
    float* a_dst1 = (float*)(W + off); off += (size_t)N_NODES * HEADS * 4;
    float* a_src2 = (float*)(W + off); off += (size_t)N_NODES * 4;
    float* a_dst2 = (float*)(W + off); off += (size_t)N_NODES * 4;
    float* out2   = (float*)(W + off); off += (size_t)N_NODES * HID * 4;                     // 12.8 MB
    float* gate   = (float*)(W + off); off += (size_t)N_NODES * 4;
    unsigned short* W1t = (unsigned short*)(W + off); off += (size_t)128 * 256 * 2;
    float* v1s = (float*)(W + off); off += 512 * 4;
    float* v1d = (float*)(W + off); off += 512 * 4;
    unsigned short* W2t = (unsigned short*)(W + off); off += (size_t)64 * 256 * 2;
    float* v2s = (float*)(W + off); off += 256 * 4;
    float* v2d = (float*)(W + off); off += 256 * 4;
    unsigned short* wg1h = (unsigned short*)(W + off); off += (size_t)64 * 64 * 2;
    unsigned short* wg1l = (unsigned short*)(W + off); off += (size_t)64 * 64 * 2;
    unsigned short* h2b = (unsigned short*)(W + off); off += (size_t)N_NODES * HID * 2;      // 6.4 MB
    (void)ws_size; (void)in_sizes; (void)n_in; (void)out_size;

    // 1: weights prep + cnt zero
    k_wprep<<<64, 256, 0, stream>>>(W1, as1, ad1, W2, as2, ad2, Wg1,
                                    W1t, v1s, v1d, W2t, v2s, v2d, wg1h, wg1l, cnt);
    // 2: gemm1 (+logit dots) | ELL build, fused by block range
    k_prep2<<<G1_TILES + ELL_BLKS, 256, 0, stream>>>(x, W1t, v1s, v1d, h1b, a_src1, a_dst1,
                                                     ei, cnt, ell);
    // 3: node1 gather + gemm2
    k_layer1<<<N_NODES / 16, 1024, 0, stream>>>(ell, cnt, (const float4*)a_src1,
        (const float4*)a_dst1, h1b, (const float4*)b1,
        (const float4*)v2s, (const float4*)v2d, W2t, a_src2, a_dst2, h2b);
    // 4: node2 gather + gate MLP
    k_layer2<<<N_NODES / 16, 1024, 0, stream>>>(ell, cnt, a_src2, a_dst2, h2b, b2,
                                                wg1h, wg1l, bg1, Wg2, bg2, out2, gate);
    // 5: per-graph softmax aggregation
    k_final<<<N_GRAPHS, 1024, 0, stream>>>(gate, out2, batch, out);
}